// Round 5
// baseline (836.017 us; speedup 1.0000x reference)
//
#include <hip/hip_runtime.h>
#include <hip/hip_bf16.h>

// Problem constants
#define N_ROWS 8192
#define DIM    2048
#define NCLS   751
#define NPAD   768     // wc padded rows (6*128)
#define KNN    6       // K+1 neighbors (incl self)
#define NCAND  12      // rescore candidates (gap(6,12) >> bf16 quant error)
#define TPAD   136     // transpose LDS stride (16B-aligned rows: 136*2=272)
#define GAP_THRESH 1.25e-3f   // bf16 rank-6/7 gap above which top-6 set is exact

typedef __attribute__((ext_vector_type(8))) short bf16x8;
typedef __attribute__((ext_vector_type(4))) float f32x4;

// ---------------------------------------------------------------------------
// async global->LDS, 16B per lane. LDS dest must be wave-uniform base + lane*16.
__device__ __forceinline__ void async_ld16(const __hip_bfloat16* g, __hip_bfloat16* l) {
    __builtin_amdgcn_global_load_lds(
        (__attribute__((address_space(1))) void*)(g),
        (__attribute__((address_space(3))) void*)(l), 16, 0, 0);
}

__device__ __forceinline__ float bf16_to_f32(short s) {
    union { float f; unsigned u; } cv;
    cv.u = ((unsigned)(unsigned short)s) << 16;
    return cv.f;
}

// ---------------------------------------------------------------------------
// Row L2 norms (f64-accurate) + bf16 normalized rows for the similarity GEMM.
__global__ void normalize_kernel(const float* __restrict__ x,
                                 __hip_bfloat16* __restrict__ xnb,
                                 double* __restrict__ invnorm) {
    int row = blockIdx.x, tid = threadIdx.x;   // 256 threads
    const float4* xr4 = (const float4*)(x + (size_t)row * DIM);
    float4 v0 = xr4[tid], v1 = xr4[tid + 256];
    double s = (double)v0.x * v0.x + (double)v0.y * v0.y +
               (double)v0.z * v0.z + (double)v0.w * v0.w +
               (double)v1.x * v1.x + (double)v1.y * v1.y +
               (double)v1.z * v1.z + (double)v1.w * v1.w;
    __shared__ double red[256];
    red[tid] = s; __syncthreads();
    for (int off = 128; off; off >>= 1) {
        if (tid < off) red[tid] += red[tid + off];
        __syncthreads();
    }
    double norm = sqrt(red[0]);
    if (norm < 1e-12) norm = 1e-12;
    double inv = 1.0 / norm;
    if (tid == 0) invnorm[row] = inv;
    float invf = (float)inv;
    __hip_bfloat16* o0 = xnb + (size_t)row * DIM + tid * 4;
    o0[0] = __float2bfloat16(v0.x * invf);
    o0[1] = __float2bfloat16(v0.y * invf);
    o0[2] = __float2bfloat16(v0.z * invf);
    o0[3] = __float2bfloat16(v0.w * invf);
    __hip_bfloat16* o1 = o0 + 1024;
    o1[0] = __float2bfloat16(v1.x * invf);
    o1[1] = __float2bfloat16(v1.y * invf);
    o1[2] = __float2bfloat16(v1.z * invf);
    o1[3] = __float2bfloat16(v1.w * invf);
}

// ---------------------------------------------------------------------------
// Triangular symmetric GEMM: S = A A^T (BK=32, R2/R4-measured: 196 us,
// conflicts 7.7e5, occupancy 28%). Upper-triangle 128x128 tiles only; off-diag
// tiles also written transposed via LDS. XOR k-chunk swizzle kills conflicts.
__global__ __launch_bounds__(256)
void gemm_syrk(const __hip_bfloat16* __restrict__ A,
               __hip_bfloat16* __restrict__ S) {
    __shared__ __align__(16) char smem[16384];
    __hip_bfloat16* As = (__hip_bfloat16*)smem;            // 128x32
    __hip_bfloat16* Bs = (__hip_bfloat16*)(smem + 8192);   // 128x32

    // decode upper-triangle tile (bi <= bj) from linear block id
    int b = blockIdx.x;
    int bi = (int)((129.0 - sqrt(16641.0 - 8.0 * (double)b)) * 0.5);
    while (64 * (bi + 1) - (bi + 1) * bi / 2 <= b) ++bi;
    while (bi > 0 && 64 * bi - bi * (bi - 1) / 2 > b) --bi;
    int bj = bi + b - (64 * bi - bi * (bi - 1) / 2);
    const size_t bm = (size_t)bi * 128, bn = (size_t)bj * 128;

    const int tid  = threadIdx.x;
    const int wave = tid >> 6, lane = tid & 63;
    const int wm = (wave & 1) * 64, wn = (wave >> 1) * 64;
    const int quad = lane >> 4, l15 = lane & 15;

    // staging maps (chunk -> row, swizzled global k-chunk)
    const int c0 = tid,        r0 = c0 >> 2, k0 = ((c0 & 3) ^ ((r0 >> 1) & 3)) * 8;
    const int c1 = tid + 256,  r1 = c1 >> 2, k1 = ((c1 & 3) ^ ((r1 >> 1) & 3)) * 8;

    f32x4 acc[4][4];
#pragma unroll
    for (int mi = 0; mi < 4; ++mi)
#pragma unroll
        for (int ni = 0; ni < 4; ++ni)
            acc[mi][ni] = (f32x4){0.f, 0.f, 0.f, 0.f};

    for (int kt = 0; kt < DIM / 32; ++kt) {
        const int kb = kt << 5;
        __syncthreads();
        async_ld16(A + (bm + r0) * (size_t)DIM + kb + k0, As + c0 * 8);
        async_ld16(A + (bm + r1) * (size_t)DIM + kb + k1, As + c1 * 8);
        async_ld16(A + (bn + r0) * (size_t)DIM + kb + k0, Bs + c0 * 8);
        async_ld16(A + (bn + r1) * (size_t)DIM + kb + k1, Bs + c1 * 8);
        __syncthreads();

        bf16x8 af[4], bfr[4];
#pragma unroll
        for (int mi = 0; mi < 4; ++mi) {
            int rr = wm + mi * 16 + l15;
            af[mi] = *(const bf16x8*)&As[(rr * 4 + (quad ^ ((rr >> 1) & 3))) * 8];
        }
#pragma unroll
        for (int ni = 0; ni < 4; ++ni) {
            int rr = wn + ni * 16 + l15;
            bfr[ni] = *(const bf16x8*)&Bs[(rr * 4 + (quad ^ ((rr >> 1) & 3))) * 8];
        }
#pragma unroll
        for (int mi = 0; mi < 4; ++mi)
#pragma unroll
            for (int ni = 0; ni < 4; ++ni)
                acc[mi][ni] = __builtin_amdgcn_mfma_f32_16x16x32_bf16(
                    af[mi], bfr[ni], acc[mi][ni], 0, 0, 0);
    }

    // direct store (C/D layout: col=lane&15, row=quad*4+e)
#pragma unroll
    for (int mi = 0; mi < 4; ++mi)
#pragma unroll
        for (int ni = 0; ni < 4; ++ni)
#pragma unroll
            for (int e = 0; e < 4; ++e) {
                size_t row = bm + wm + mi * 16 + quad * 4 + e;
                size_t col = bn + wn + ni * 16 + l15;
                S[row * N_ROWS + col] = __float2bfloat16(acc[mi][ni][e]);
            }

    if (bi != bj) {
        // transposed tile via LDS (4 passes of 32 cols), vector stores
        __hip_bfloat16* T = (__hip_bfloat16*)smem;   // 32 x TPAD bf16
#pragma unroll
        for (int p = 0; p < 4; ++p) {
            __syncthreads();
            if (wn == ((p >= 2) ? 64 : 0)) {
                const int ni0 = (p & 1) * 2;
#pragma unroll
                for (int nio = 0; nio < 2; ++nio) {
                    const int ni = ni0 + nio;
                    const int tc = ni * 16 + l15 + wn - p * 32;   // 0..31
#pragma unroll
                    for (int mi = 0; mi < 4; ++mi)
#pragma unroll
                        for (int e = 0; e < 4; ++e) {
                            int r = wm + mi * 16 + quad * 4 + e;
                            T[tc * TPAD + r] = __float2bfloat16(acc[mi][ni][e]);
                        }
                }
            }
            __syncthreads();
#pragma unroll
            for (int j2 = 0; j2 < 2; ++j2) {
                int q = tid + 256 * j2;           // 0..511
                int tc = q >> 4, r8 = (q & 15) * 8;
                *(bf16x8*)&S[(bn + p * 32 + tc) * N_ROWS + bm + r8] =
                    *(const bf16x8*)&T[tc * TPAD + r8];
            }
        }
    }
}

// ---------------------------------------------------------------------------
// Generic NT bf16 GEMM, BK=32, XOR-swizzled LDS. C[M,N] = A[M,K] * B[N,K]^T.
// TM = rows per block (128 or 64). EPI:
//   1 = relu(v+bias) -> bf16
//   4 = v+bias -> bf16, plus per-column sum/sumsq atomics into stats (BN)
//   5 = v+bias -> fp32, col<ncols guard (classifier with folded BN)
template <int EPI, int TM>
__global__ __launch_bounds__(256)
void gemm_nt(const __hip_bfloat16* __restrict__ A,
             const __hip_bfloat16* __restrict__ B,
             void* __restrict__ Cv,
             const float* __restrict__ bias,
             float* __restrict__ stats,
             int K, int ldc, int ncols) {
    constexpr int MI = TM / 32;                       // 4 or 2
    __shared__ __align__(16) char smem[TM * 64 + 8192];
    __hip_bfloat16* As = (__hip_bfloat16*)smem;               // TM x 32
    __hip_bfloat16* Bs = (__hip_bfloat16*)(smem + TM * 64);   // 128 x 32
    const int tid  = threadIdx.x;
    const size_t bm = (size_t)blockIdx.y * TM, bn = (size_t)blockIdx.x * 128;
    const int wave = tid >> 6, lane = tid & 63;
    const int wm = (wave & 1) * (TM / 2), wn = (wave >> 1) * 64;
    const int quad = lane >> 4, l15 = lane & 15;

    const int ca  = tid,       ra  = ca  >> 2, ka  = ((ca  & 3) ^ ((ra  >> 1) & 3)) * 8;
    const int ca2 = tid + 256, ra2 = ca2 >> 2, ka2 = ((ca2 & 3) ^ ((ra2 >> 1) & 3)) * 8;

    f32x4 acc[MI][4];
#pragma unroll
    for (int mi = 0; mi < MI; ++mi)
#pragma unroll
        for (int ni = 0; ni < 4; ++ni)
            acc[mi][ni] = (f32x4){0.f, 0.f, 0.f, 0.f};

    const int KT = K >> 5;
    for (int kt = 0; kt < KT; ++kt) {
        const int kb = kt << 5;
        __syncthreads();
        async_ld16(A + (bm + ra) * (size_t)K + kb + ka, As + ca * 8);
        if (TM == 128)
            async_ld16(A + (bm + ra2) * (size_t)K + kb + ka2, As + ca2 * 8);
        async_ld16(B + (bn + ra) * (size_t)K + kb + ka, Bs + ca * 8);
        async_ld16(B + (bn + ra2) * (size_t)K + kb + ka2, Bs + ca2 * 8);
        __syncthreads();

        bf16x8 af[MI], bfr[4];
#pragma unroll
        for (int mi = 0; mi < MI; ++mi) {
            int rr = wm + mi * 16 + l15;
            af[mi] = *(const bf16x8*)&As[(rr * 4 + (quad ^ ((rr >> 1) & 3))) * 8];
        }
#pragma unroll
        for (int ni = 0; ni < 4; ++ni) {
            int rr = wn + ni * 16 + l15;
            bfr[ni] = *(const bf16x8*)&Bs[(rr * 4 + (quad ^ ((rr >> 1) & 3))) * 8];
        }
#pragma unroll
        for (int mi = 0; mi < MI; ++mi)
#pragma unroll
            for (int ni = 0; ni < 4; ++ni)
                acc[mi][ni] = __builtin_amdgcn_mfma_f32_16x16x32_bf16(
                    af[mi], bfr[ni], acc[mi][ni], 0, 0, 0);
    }

    float s1[4] = {0.f, 0.f, 0.f, 0.f}, s2[4] = {0.f, 0.f, 0.f, 0.f};
#pragma unroll
    for (int mi = 0; mi < MI; ++mi)
#pragma unroll
        for (int ni = 0; ni < 4; ++ni)
#pragma unroll
            for (int e = 0; e < 4; ++e) {
                size_t row = bm + wm + mi * 16 + quad * 4 + e;
                int col = (int)(bn + wn + ni * 16 + l15);
                float v = acc[mi][ni][e];
                if (EPI == 1) {
                    v += bias[col]; v = v > 0.f ? v : 0.f;
                    ((__hip_bfloat16*)Cv)[row * (size_t)ldc + col] = __float2bfloat16(v);
                } else if (EPI == 4) {
                    v += bias[col];
                    ((__hip_bfloat16*)Cv)[row * (size_t)ldc + col] = __float2bfloat16(v);
                    s1[ni] += v; s2[ni] += v * v;    // exact (pre-quantization) stats
                } else {
                    v += bias[col];
                    if (col < ncols)
                        ((float*)Cv)[row * (size_t)ldc + col] = v;
                }
            }

    if (EPI == 4) {
        // column sums: quad-butterfly, LDS merge over the two wm halves, atomics
        __syncthreads();                    // all waves done with As/Bs
        float* sred = (float*)smem;         // [2 halves][128 cols][2 stats]
#pragma unroll
        for (int ni = 0; ni < 4; ++ni) {
            float a = s1[ni], bq = s2[ni];
            a += __shfl_xor(a, 16);  a += __shfl_xor(a, 32);
            bq += __shfl_xor(bq, 16); bq += __shfl_xor(bq, 32);
            if (lane < 16) {
                int c = wn + ni * 16 + l15;
                sred[((wave & 1) * 128 + c) * 2 + 0] = a;
                sred[((wave & 1) * 128 + c) * 2 + 1] = bq;
            }
        }
        __syncthreads();
        if (tid < 128) {
            float ta = sred[tid * 2] + sred[(128 + tid) * 2];
            float tb = sred[tid * 2 + 1] + sred[(128 + tid) * 2 + 1];
            atomicAdd(&stats[bn + tid], ta);
            atomicAdd(&stats[DIM + bn + tid], tb);
        }
    }
}

// ---------------------------------------------------------------------------
// Per-row top-NCAND candidates from bf16 similarity row. 1 wave per row.
// Fast path: single compare vs running 6th-best; insert is rare (~6/t decay).
// Confident-row shortcut: if bf16 gap(rank6, rank7) >= GAP_THRESH, the bf16
// top-6 SET is provably the fp32 top-6 set -> write idx6 directly; else
// append row to the rescore worklist.
__global__ void topk_cand_kernel(const __hip_bfloat16* __restrict__ S,
                                 int* __restrict__ cand,
                                 int* __restrict__ idx6,
                                 int* __restrict__ wl,
                                 int* __restrict__ cnt) {
    int row = blockIdx.x, lane = threadIdx.x;   // 64 threads
    const bf16x8* Sr8 = (const bf16x8*)(S + (size_t)row * N_ROWS);
    float bv[6]; int bi6[6];
#pragma unroll
    for (int t = 0; t < 6; ++t) { bv[t] = -1e30f; bi6[t] = -1; }
    float vmin = -1e30f;
    for (int it = 0; it < N_ROWS / (64 * 8); ++it) {
        int c8 = it * 64 + lane;
        bf16x8 v8 = Sr8[c8];
#pragma unroll
        for (int u = 0; u < 8; ++u) {
            float v = bf16_to_f32(v8[u]);
            if (v > vmin) {
                int ms = 0; float mv = bv[0];
#pragma unroll
                for (int t = 1; t < 6; ++t) if (bv[t] < mv) { mv = bv[t]; ms = t; }
                bv[ms] = v; bi6[ms] = c8 * 8 + u;
                vmin = bv[0];
#pragma unroll
                for (int t = 1; t < 6; ++t) vmin = fminf(vmin, bv[t]);
            }
        }
    }
    __shared__ float sv[384];
    __shared__ int   si[384];
    __shared__ float topv[NCAND];
    __shared__ int   topi[NCAND];
#pragma unroll
    for (int t = 0; t < 6; ++t) { sv[lane * 6 + t] = bv[t]; si[lane * 6 + t] = bi6[t]; }
    __syncthreads();
    for (int t = 0; t < NCAND; ++t) {
        float m = -1e30f; int mpos = -1, midx = 0x7fffffff;
        for (int e = lane; e < 384; e += 64) {
            float v = sv[e]; int ix = si[e];
            if (v > m || (v == m && ix < midx)) { m = v; mpos = e; midx = ix; }
        }
#pragma unroll
        for (int off = 32; off; off >>= 1) {
            float ov = __shfl_xor(m, off);
            int   op = __shfl_xor(mpos, off);
            int   oi = __shfl_xor(midx, off);
            if (ov > m || (ov == m && oi < midx)) { m = ov; mpos = op; midx = oi; }
        }
        if (lane == 0) {
            cand[row * NCAND + t] = midx;
            topv[t] = m; topi[t] = midx;
            sv[mpos] = -1e30f;
        }
        __syncthreads();
    }
    if (lane == 0) {
        if (topv[KNN - 1] - topv[KNN] >= GAP_THRESH) {
#pragma unroll
            for (int t = 0; t < KNN; ++t) idx6[row * KNN + t] = topi[t];
        } else {
            int p = atomicAdd(cnt, 1);
            wl[p] = row;
        }
    }
}

// ---------------------------------------------------------------------------
// Exact (f64) rescore of ambiguous rows only (worklist-driven; early-exit
// past count). 256 threads, wave w handles candidates w, w+4, w+8.
__global__ void rescore_kernel(const float* __restrict__ x,
                               const double* __restrict__ invnorm,
                               const int* __restrict__ cand,
                               const int* __restrict__ wl,
                               const int* __restrict__ cnt,
                               int* __restrict__ idx6) {
    if (blockIdx.x >= *cnt) return;          // uniform per block
    int row = wl[blockIdx.x];
    int tid = threadIdx.x;                   // 256 threads
    int wave = tid >> 6, lane = tid & 63;
    __shared__ float4 xi4[DIM / 4];
    __shared__ double simv[NCAND];
    __shared__ int    cnd[NCAND];
    const float4* xr4 = (const float4*)(x + (size_t)row * DIM);
    xi4[tid] = xr4[tid]; xi4[tid + 256] = xr4[tid + 256];
    if (tid < NCAND) cnd[tid] = cand[row * NCAND + tid];
    __syncthreads();
    for (int t = wave; t < NCAND; t += 4) {
        int j = cnd[t];
        if (j == row) { if (lane == 0) simv[t] = 1e30; continue; }  // self: rank 1
        const float4* xj4 = (const float4*)(x + (size_t)j * DIM);
        double s = 0.0;
        for (int k = lane; k < DIM / 4; k += 64) {
            float4 a = xj4[k], bq = xi4[k];
            s += (double)a.x * bq.x + (double)a.y * bq.y +
                 (double)a.z * bq.z + (double)a.w * bq.w;
        }
#pragma unroll
        for (int off = 32; off; off >>= 1) s += __shfl_xor(s, off);
        if (lane == 0) simv[t] = s * invnorm[row] * invnorm[j];
    }
    __syncthreads();
    if (tid == 0) {
        double vals[NCAND]; int idxs[NCAND];
        for (int t = 0; t < NCAND; ++t) { vals[t] = simv[t]; idxs[t] = cnd[t]; }
        for (int t = 0; t < KNN; ++t) {
            int best = 0; double bvv = -1e300; int bji = 0x7fffffff;
            for (int e = 0; e < NCAND; ++e) {
                if (vals[e] > bvv || (vals[e] == bvv && idxs[e] < bji)) {
                    bvv = vals[e]; best = e; bji = idxs[e];
                }
            }
            idx6[row * KNN + t] = idxs[best];
            vals[best] = -1e300;
        }
    }
}

// ---------------------------------------------------------------------------
// GIN aggregation with reciprocal mask: h0 = 1.3*x_i + sum reciprocal x_j -> bf16
__global__ void aggregate_kernel(const float* __restrict__ x,
                                 const int* __restrict__ idx6,
                                 __hip_bfloat16* __restrict__ h0) {
    int row = blockIdx.x, tid = threadIdx.x;   // 256 threads
    __shared__ int nb[KNN];
    __shared__ int fl[KNN];
    if (tid < KNN) {
        int j = idx6[row * KNN + tid];
        nb[tid] = j;
        int f = 0;
        for (int t = 0; t < KNN; ++t) if (idx6[j * KNN + t] == row) f = 1;
        fl[tid] = f;
    }
    __syncthreads();
    int f0 = tid * 8;
    const float4* xr4 = (const float4*)(x + (size_t)row * DIM + f0);
    float4 a0 = xr4[0], a1 = xr4[1];
    float acc[8] = {1.3f * a0.x, 1.3f * a0.y, 1.3f * a0.z, 1.3f * a0.w,
                    1.3f * a1.x, 1.3f * a1.y, 1.3f * a1.z, 1.3f * a1.w};
    for (int t = 0; t < KNN; ++t) {
        if (fl[t]) {
            const float4* xj4 = (const float4*)(x + (size_t)nb[t] * DIM + f0);
            float4 b0 = xj4[0], b1 = xj4[1];
            acc[0] += b0.x; acc[1] += b0.y; acc[2] += b0.z; acc[3] += b0.w;
            acc[4] += b1.x; acc[5] += b1.y; acc[6] += b1.z; acc[7] += b1.w;
        }
    }
#pragma unroll
    for (int u = 0; u < 8; ++u)
        h0[(size_t)row * DIM + f0 + u] = __float2bfloat16(acc[u]);
}

// ---------------------------------------------------------------------------
__global__ void bn_finalize_kernel(float* __restrict__ stats,
                                   const float* __restrict__ gamma,
                                   const float* __restrict__ beta) {
    int c = blockIdx.x * 256 + threadIdx.x;         // 2048
    float mean = stats[c] * (1.0f / 8192.0f);
    float var  = stats[DIM + c] * (1.0f / 8192.0f) - mean * mean;
    float sc   = gamma[c] / sqrtf(var + 1e-5f);
    stats[2 * DIM + c] = sc;                        // scale
    stats[3 * DIM + c] = beta[c] - mean * sc;       // shift
}

// Fold BN into classifier: wcs[c,k] = wc[c,k]*scale[k] (bf16, zero-padded rows),
// lb[c] = sum_k shift[k]*wc[c,k].
__global__ void wc_fold_kernel(const float* __restrict__ wc,
                               const float* __restrict__ stats,
                               __hip_bfloat16* __restrict__ wcs,
                               float* __restrict__ lb) {
    int r = blockIdx.x, tid = threadIdx.x;          // 768 blocks x 256
    int k0 = tid * 8;
    float part = 0.f;
    if (r < NCLS) {
#pragma unroll
        for (int u = 0; u < 8; ++u) {
            int k = k0 + u;
            float w = wc[(size_t)r * DIM + k];
            wcs[(size_t)r * DIM + k] = __float2bfloat16(w * stats[2 * DIM + k]);
            part += w * stats[3 * DIM + k];
        }
    } else {
#pragma unroll
        for (int u = 0; u < 8; ++u)
            wcs[(size_t)r * DIM + k0 + u] = __float2bfloat16(0.f);
    }
    __shared__ float red[256];
    red[tid] = part; __syncthreads();
    for (int off = 128; off; off >>= 1) {
        if (tid < off) red[tid] += red[tid + off];
        __syncthreads();
    }
    if (tid == 0) lb[r] = red[0];
}

// ---------------------------------------------------------------------------
__global__ void f32_to_bf16_kernel(const float* __restrict__ src,
                                   __hip_bfloat16* __restrict__ dst, int n4) {
    int i = blockIdx.x * 256 + threadIdx.x;
    if (i < n4) {
        float4 v = ((const float4*)src)[i];
        __hip_bfloat16* o = dst + (size_t)i * 4;
        o[0] = __float2bfloat16(v.x); o[1] = __float2bfloat16(v.y);
        o[2] = __float2bfloat16(v.z); o[3] = __float2bfloat16(v.w);
    }
}

// ---------------------------------------------------------------------------
extern "C" void kernel_launch(void* const* d_in, const int* in_sizes, int n_in,
                              void* d_out, int out_size, void* d_ws, size_t ws_size,
                              hipStream_t stream) {
    const float* x     = (const float*)d_in[0];
    const float* w1    = (const float*)d_in[1];
    const float* b1    = (const float*)d_in[2];
    const float* w2    = (const float*)d_in[3];
    const float* b2    = (const float*)d_in[4];
    const float* gamma = (const float*)d_in[5];
    const float* beta  = (const float*)d_in[6];
    const float* wc    = (const float*)d_in[7];
    float* out = (float*)d_out;

    char* ws = (char*)d_ws;
    size_t off = 0;
    auto alloc = [&](size_t bytes) -> void* {
        void* p = ws + off;
        off += (bytes + 255) & ~(size_t)255;
        return p;
    };

    __hip_bfloat16* xnb  = (__hip_bfloat16*)alloc((size_t)N_ROWS * DIM * 2);    // 32 MB (reused: h0)
    __hip_bfloat16* S    = (__hip_bfloat16*)alloc((size_t)N_ROWS * N_ROWS * 2); // 128 MB (reused: z1, z2b)
    double*         invn = (double*)alloc((size_t)N_ROWS * 8);
    int*            cand = (int*)alloc((size_t)N_ROWS * NCAND * 4);
    int*            idx6 = (int*)alloc((size_t)N_ROWS * KNN * 4);
    __hip_bfloat16* w1b  = (__hip_bfloat16*)alloc((size_t)DIM * DIM * 2);
    __hip_bfloat16* w2b  = (__hip_bfloat16*)alloc((size_t)DIM * DIM * 2);
    __hip_bfloat16* wcs  = (__hip_bfloat16*)alloc((size_t)NPAD * DIM * 2);
    float*          lb   = (float*)alloc((size_t)NPAD * 4);
    float*          stats = (float*)alloc((size_t)4 * DIM * 4);
    int*            wl   = (int*)alloc((size_t)N_ROWS * 4);
    int*            cnt  = (int*)alloc((size_t)256);

    __hip_bfloat16* h0  = xnb;                          // xn dead after syrk
    __hip_bfloat16* z1  = S;                            // S dead after topk
    __hip_bfloat16* z2b = S + (size_t)N_ROWS * DIM;     // next 32 MB of S region

    hipMemsetAsync(stats, 0, 2 * DIM * sizeof(float), stream);
    hipMemsetAsync(cnt, 0, sizeof(int), stream);

    normalize_kernel<<<N_ROWS, 256, 0, stream>>>(x, xnb, invn);
    f32_to_bf16_kernel<<<(DIM * DIM / 4) / 256, 256, 0, stream>>>(w1, w1b, DIM * DIM / 4);
    f32_to_bf16_kernel<<<(DIM * DIM / 4) / 256, 256, 0, stream>>>(w2, w2b, DIM * DIM / 4);

    // S = xn xn^T, upper-triangle tiles only (+transposed writes)
    gemm_syrk<<<2080, 256, 0, stream>>>(xnb, S);

    topk_cand_kernel<<<N_ROWS, 64, 0, stream>>>(S, cand, idx6, wl, cnt);
    rescore_kernel<<<N_ROWS, 256, 0, stream>>>(x, invn, cand, wl, cnt, idx6);
    aggregate_kernel<<<N_ROWS, 256, 0, stream>>>(x, idx6, h0);

    // z1 = relu(h0 @ w1^T + b1)   [bf16]
    gemm_nt<1, 128><<<dim3(DIM / 128, N_ROWS / 128), 256, 0, stream>>>(
        h0, w1b, (void*)z1, b1, nullptr, DIM, DIM, 0);
    // z2b = h@w2^T + b2 [bf16] with fused BN column stats
    gemm_nt<4, 128><<<dim3(DIM / 128, N_ROWS / 128), 256, 0, stream>>>(
        z1, w2b, (void*)z2b, b2, stats, DIM, DIM, 0);

    bn_finalize_kernel<<<DIM / 256, 256, 0, stream>>>(stats, gamma, beta);
    wc_fold_kernel<<<NPAD, 256, 0, stream>>>(wc, stats, wcs, lb);

    // logits = (z2*scale+shift) @ wc^T = z2b @ wcs^T + lb   [fp32, col<751]
    gemm_nt<5, 64><<<dim3(NPAD / 128, N_ROWS / 64), 256, 0, stream>>>(
        z2b, wcs, (void*)out, lb, nullptr, DIM, NCLS, NCLS);
}

// Round 6
// 762.827 us; speedup vs baseline: 1.0959x; 1.0959x over previous
//
#include <hip/hip_runtime.h>
#include <hip/hip_bf16.h>

// Problem constants
#define N_ROWS 8192
#define DIM    2048
#define NCLS   751
#define NPAD   768     // wc padded rows (6*128)
#define KNN    6       // K+1 neighbors (incl self)
#define NCAND  12      // rescore candidates (gap(6,12) >> bf16 quant error)
#define TPAD   136     // transpose LDS stride (16B-aligned rows: 136*2=272)
#define GAP_THRESH 1.25e-3f   // bf16 rank-6/7 gap above which top-6 set is exact

typedef __attribute__((ext_vector_type(8))) short bf16x8;
typedef __attribute__((ext_vector_type(4))) float f32x4;

// ---------------------------------------------------------------------------
// async global->LDS, 16B per lane. LDS dest must be wave-uniform base + lane*16.
__device__ __forceinline__ void async_ld16(const __hip_bfloat16* g, __hip_bfloat16* l) {
    __builtin_amdgcn_global_load_lds(
        (__attribute__((address_space(1))) void*)(g),
        (__attribute__((address_space(3))) void*)(l), 16, 0, 0);
}

__device__ __forceinline__ float bf16_to_f32(short s) {
    union { float f; unsigned u; } cv;
    cv.u = ((unsigned)(unsigned short)s) << 16;
    return cv.f;
}

// ---------------------------------------------------------------------------
// Row L2 norms (f64-accurate) + bf16 normalized rows for the similarity GEMM.
__global__ void normalize_kernel(const float* __restrict__ x,
                                 __hip_bfloat16* __restrict__ xnb,
                                 double* __restrict__ invnorm) {
    int row = blockIdx.x, tid = threadIdx.x;   // 256 threads
    const float4* xr4 = (const float4*)(x + (size_t)row * DIM);
    float4 v0 = xr4[tid], v1 = xr4[tid + 256];
    double s = (double)v0.x * v0.x + (double)v0.y * v0.y +
               (double)v0.z * v0.z + (double)v0.w * v0.w +
               (double)v1.x * v1.x + (double)v1.y * v1.y +
               (double)v1.z * v1.z + (double)v1.w * v1.w;
    __shared__ double red[256];
    red[tid] = s; __syncthreads();
    for (int off = 128; off; off >>= 1) {
        if (tid < off) red[tid] += red[tid + off];
        __syncthreads();
    }
    double norm = sqrt(red[0]);
    if (norm < 1e-12) norm = 1e-12;
    double inv = 1.0 / norm;
    if (tid == 0) invnorm[row] = inv;
    float invf = (float)inv;
    __hip_bfloat16* o0 = xnb + (size_t)row * DIM + tid * 4;
    o0[0] = __float2bfloat16(v0.x * invf);
    o0[1] = __float2bfloat16(v0.y * invf);
    o0[2] = __float2bfloat16(v0.z * invf);
    o0[3] = __float2bfloat16(v0.w * invf);
    __hip_bfloat16* o1 = o0 + 1024;
    o1[0] = __float2bfloat16(v1.x * invf);
    o1[1] = __float2bfloat16(v1.y * invf);
    o1[2] = __float2bfloat16(v1.z * invf);
    o1[3] = __float2bfloat16(v1.w * invf);
}

// ---------------------------------------------------------------------------
// Triangular symmetric GEMM: S = A A^T (BK=32, R2/R4/R5-measured: 196 us,
// conflicts 7.7e5, occupancy 28%). Upper-triangle 128x128 tiles only; off-diag
// tiles also written transposed via LDS. XOR k-chunk swizzle kills conflicts.
// NOTE: syrk stays BK=32 (grid 2080 wants ~8 blocks/CU; BK=64 cut occupancy
// to 18.8% and regressed to 216 us in R3). gemm_nt below is BK=64 (grid-
// limited to 4 blocks/CU, occupancy unaffected, halved barrier drains).
__global__ __launch_bounds__(256)
void gemm_syrk(const __hip_bfloat16* __restrict__ A,
               __hip_bfloat16* __restrict__ S) {
    __shared__ __align__(16) char smem[16384];
    __hip_bfloat16* As = (__hip_bfloat16*)smem;            // 128x32
    __hip_bfloat16* Bs = (__hip_bfloat16*)(smem + 8192);   // 128x32

    // decode upper-triangle tile (bi <= bj) from linear block id
    int b = blockIdx.x;
    int bi = (int)((129.0 - sqrt(16641.0 - 8.0 * (double)b)) * 0.5);
    while (64 * (bi + 1) - (bi + 1) * bi / 2 <= b) ++bi;
    while (bi > 0 && 64 * bi - bi * (bi - 1) / 2 > b) --bi;
    int bj = bi + b - (64 * bi - bi * (bi - 1) / 2);
    const size_t bm = (size_t)bi * 128, bn = (size_t)bj * 128;

    const int tid  = threadIdx.x;
    const int wave = tid >> 6, lane = tid & 63;
    const int wm = (wave & 1) * 64, wn = (wave >> 1) * 64;
    const int quad = lane >> 4, l15 = lane & 15;

    // staging maps (chunk -> row, swizzled global k-chunk)
    const int c0 = tid,        r0 = c0 >> 2, k0 = ((c0 & 3) ^ ((r0 >> 1) & 3)) * 8;
    const int c1 = tid + 256,  r1 = c1 >> 2, k1 = ((c1 & 3) ^ ((r1 >> 1) & 3)) * 8;

    f32x4 acc[4][4];
#pragma unroll
    for (int mi = 0; mi < 4; ++mi)
#pragma unroll
        for (int ni = 0; ni < 4; ++ni)
            acc[mi][ni] = (f32x4){0.f, 0.f, 0.f, 0.f};

    for (int kt = 0; kt < DIM / 32; ++kt) {
        const int kb = kt << 5;
        __syncthreads();
        async_ld16(A + (bm + r0) * (size_t)DIM + kb + k0, As + c0 * 8);
        async_ld16(A + (bm + r1) * (size_t)DIM + kb + k1, As + c1 * 8);
        async_ld16(A + (bn + r0) * (size_t)DIM + kb + k0, Bs + c0 * 8);
        async_ld16(A + (bn + r1) * (size_t)DIM + kb + k1, Bs + c1 * 8);
        __syncthreads();

        bf16x8 af[4], bfr[4];
#pragma unroll
        for (int mi = 0; mi < 4; ++mi) {
            int rr = wm + mi * 16 + l15;
            af[mi] = *(const bf16x8*)&As[(rr * 4 + (quad ^ ((rr >> 1) & 3))) * 8];
        }
#pragma unroll
        for (int ni = 0; ni < 4; ++ni) {
            int rr = wn + ni * 16 + l15;
            bfr[ni] = *(const bf16x8*)&Bs[(rr * 4 + (quad ^ ((rr >> 1) & 3))) * 8];
        }
#pragma unroll
        for (int mi = 0; mi < 4; ++mi)
#pragma unroll
            for (int ni = 0; ni < 4; ++ni)
                acc[mi][ni] = __builtin_amdgcn_mfma_f32_16x16x32_bf16(
                    af[mi], bfr[ni], acc[mi][ni], 0, 0, 0);
    }

    // direct store (C/D layout: col=lane&15, row=quad*4+e)
#pragma unroll
    for (int mi = 0; mi < 4; ++mi)
#pragma unroll
        for (int ni = 0; ni < 4; ++ni)
#pragma unroll
            for (int e = 0; e < 4; ++e) {
                size_t row = bm + wm + mi * 16 + quad * 4 + e;
                size_t col = bn + wn + ni * 16 + l15;
                S[row * N_ROWS + col] = __float2bfloat16(acc[mi][ni][e]);
            }

    if (bi != bj) {
        // transposed tile via LDS (4 passes of 32 cols), vector stores
        __hip_bfloat16* T = (__hip_bfloat16*)smem;   // 32 x TPAD bf16
#pragma unroll
        for (int p = 0; p < 4; ++p) {
            __syncthreads();
            if (wn == ((p >= 2) ? 64 : 0)) {
                const int ni0 = (p & 1) * 2;
#pragma unroll
                for (int nio = 0; nio < 2; ++nio) {
                    const int ni = ni0 + nio;
                    const int tc = ni * 16 + l15 + wn - p * 32;   // 0..31
#pragma unroll
                    for (int mi = 0; mi < 4; ++mi)
#pragma unroll
                        for (int e = 0; e < 4; ++e) {
                            int r = wm + mi * 16 + quad * 4 + e;
                            T[tc * TPAD + r] = __float2bfloat16(acc[mi][ni][e]);
                        }
                }
            }
            __syncthreads();
#pragma unroll
            for (int j2 = 0; j2 < 2; ++j2) {
                int q = tid + 256 * j2;           // 0..511
                int tc = q >> 4, r8 = (q & 15) * 8;
                *(bf16x8*)&S[(bn + p * 32 + tc) * N_ROWS + bm + r8] =
                    *(const bf16x8*)&T[tc * TPAD + r8];
            }
        }
    }
}

// ---------------------------------------------------------------------------
// Generic NT bf16 GEMM, BK=64 (R3-measured best for these grid-limited
// shapes: <=1024 blocks -> 4 blocks/CU, LDS cap 5, so 32 KB LDS is free and
// barrier drains halve). XOR-swizzled LDS: chunk slot = gchunk ^ (row&7).
// C[M,N] = A[M,K] * B[N,K]^T. TM = rows per block (128 or 64). EPI:
//   1 = relu(v+bias) -> bf16
//   4 = v+bias -> bf16, plus per-column sum/sumsq atomics into stats (BN)
//   5 = v+bias -> fp32, col<ncols guard (classifier with folded BN)
template <int EPI, int TM>
__global__ __launch_bounds__(256)
void gemm_nt(const __hip_bfloat16* __restrict__ A,
             const __hip_bfloat16* __restrict__ B,
             void* __restrict__ Cv,
             const float* __restrict__ bias,
             float* __restrict__ stats,
             int K, int ldc, int ncols) {
    constexpr int MI = TM / 32;                       // 4 or 2
    __shared__ __align__(16) char smem[TM * 128 + 16384];
    __hip_bfloat16* As = (__hip_bfloat16*)smem;                // TM x 64
    __hip_bfloat16* Bs = (__hip_bfloat16*)(smem + TM * 128);   // 128 x 64
    const int tid  = threadIdx.x;
    const size_t bm = (size_t)blockIdx.y * TM, bn = (size_t)blockIdx.x * 128;
    const int wave = tid >> 6, lane = tid & 63;
    const int wm = (wave & 1) * (TM / 2), wn = (wave >> 1) * 64;
    const int quad = lane >> 4, l15 = lane & 15;

    f32x4 acc[MI][4];
#pragma unroll
    for (int mi = 0; mi < MI; ++mi)
#pragma unroll
        for (int ni = 0; ni < 4; ++ni)
            acc[mi][ni] = (f32x4){0.f, 0.f, 0.f, 0.f};

    const int KT = K >> 6;
    for (int kt = 0; kt < KT; ++kt) {
        const int kb = kt << 6;
        __syncthreads();
#pragma unroll
        for (int j = 0; j < TM / 32; ++j) {
            int q = tid + 256 * j, r = q >> 3, g = ((q & 7) ^ (r & 7)) * 8;
            async_ld16(A + (bm + r) * (size_t)K + kb + g, As + q * 8);
        }
#pragma unroll
        for (int j = 0; j < 4; ++j) {
            int q = tid + 256 * j, r = q >> 3, g = ((q & 7) ^ (r & 7)) * 8;
            async_ld16(B + (bn + r) * (size_t)K + kb + g, Bs + q * 8);
        }
        __syncthreads();

#pragma unroll
        for (int s = 0; s < 2; ++s) {
            bf16x8 af[MI], bfr[4];
#pragma unroll
            for (int mi = 0; mi < MI; ++mi) {
                int rr = wm + mi * 16 + l15;
                af[mi] = *(const bf16x8*)&As[(rr * 8 + ((s * 4 + quad) ^ (rr & 7))) * 8];
            }
#pragma unroll
            for (int ni = 0; ni < 4; ++ni) {
                int rr = wn + ni * 16 + l15;
                bfr[ni] = *(const bf16x8*)&Bs[(rr * 8 + ((s * 4 + quad) ^ (rr & 7))) * 8];
            }
#pragma unroll
            for (int mi = 0; mi < MI; ++mi)
#pragma unroll
                for (int ni = 0; ni < 4; ++ni)
                    acc[mi][ni] = __builtin_amdgcn_mfma_f32_16x16x32_bf16(
                        af[mi], bfr[ni], acc[mi][ni], 0, 0, 0);
        }
    }

    float s1[4] = {0.f, 0.f, 0.f, 0.f}, s2[4] = {0.f, 0.f, 0.f, 0.f};
#pragma unroll
    for (int mi = 0; mi < MI; ++mi)
#pragma unroll
        for (int ni = 0; ni < 4; ++ni)
#pragma unroll
            for (int e = 0; e < 4; ++e) {
                size_t row = bm + wm + mi * 16 + quad * 4 + e;
                int col = (int)(bn + wn + ni * 16 + l15);
                float v = acc[mi][ni][e];
                if (EPI == 1) {
                    v += bias[col]; v = v > 0.f ? v : 0.f;
                    ((__hip_bfloat16*)Cv)[row * (size_t)ldc + col] = __float2bfloat16(v);
                } else if (EPI == 4) {
                    v += bias[col];
                    ((__hip_bfloat16*)Cv)[row * (size_t)ldc + col] = __float2bfloat16(v);
                    s1[ni] += v; s2[ni] += v * v;    // exact (pre-quantization) stats
                } else {
                    v += bias[col];
                    if (col < ncols)
                        ((float*)Cv)[row * (size_t)ldc + col] = v;
                }
            }

    if (EPI == 4) {
        // column sums: quad-butterfly, LDS merge over the two wm halves, atomics
        __syncthreads();                    // all waves done with As/Bs
        float* sred = (float*)smem;         // [2 halves][128 cols][2 stats]
#pragma unroll
        for (int ni = 0; ni < 4; ++ni) {
            float a = s1[ni], bq = s2[ni];
            a += __shfl_xor(a, 16);  a += __shfl_xor(a, 32);
            bq += __shfl_xor(bq, 16); bq += __shfl_xor(bq, 32);
            if (lane < 16) {
                int c = wn + ni * 16 + l15;
                sred[((wave & 1) * 128 + c) * 2 + 0] = a;
                sred[((wave & 1) * 128 + c) * 2 + 1] = bq;
            }
        }
        __syncthreads();
        if (tid < 128) {
            float ta = sred[tid * 2] + sred[(128 + tid) * 2];
            float tb = sred[tid * 2 + 1] + sred[(128 + tid) * 2 + 1];
            atomicAdd(&stats[bn + tid], ta);
            atomicAdd(&stats[DIM + bn + tid], tb);
        }
    }
}

// ---------------------------------------------------------------------------
// Per-row top-NCAND candidates from bf16 similarity row. 1 wave per row.
// Fast path: single compare vs running 6th-best; insert is rare (~6/t decay).
// Confident-row shortcut: if bf16 gap(rank6, rank7) >= GAP_THRESH, the bf16
// top-6 SET is provably the fp32 top-6 set -> write idx6 directly; else
// append row to the rescore worklist.
__global__ void topk_cand_kernel(const __hip_bfloat16* __restrict__ S,
                                 int* __restrict__ cand,
                                 int* __restrict__ idx6,
                                 int* __restrict__ wl,
                                 int* __restrict__ cnt) {
    int row = blockIdx.x, lane = threadIdx.x;   // 64 threads
    const bf16x8* Sr8 = (const bf16x8*)(S + (size_t)row * N_ROWS);
    float bv[6]; int bi6[6];
#pragma unroll
    for (int t = 0; t < 6; ++t) { bv[t] = -1e30f; bi6[t] = -1; }
    float vmin = -1e30f;
    for (int it = 0; it < N_ROWS / (64 * 8); ++it) {
        int c8 = it * 64 + lane;
        bf16x8 v8 = Sr8[c8];
#pragma unroll
        for (int u = 0; u < 8; ++u) {
            float v = bf16_to_f32(v8[u]);
            if (v > vmin) {
                int ms = 0; float mv = bv[0];
#pragma unroll
                for (int t = 1; t < 6; ++t) if (bv[t] < mv) { mv = bv[t]; ms = t; }
                bv[ms] = v; bi6[ms] = c8 * 8 + u;
                vmin = bv[0];
#pragma unroll
                for (int t = 1; t < 6; ++t) vmin = fminf(vmin, bv[t]);
            }
        }
    }
    __shared__ float sv[384];
    __shared__ int   si[384];
    __shared__ float topv[NCAND];
    __shared__ int   topi[NCAND];
#pragma unroll
    for (int t = 0; t < 6; ++t) { sv[lane * 6 + t] = bv[t]; si[lane * 6 + t] = bi6[t]; }
    __syncthreads();
    for (int t = 0; t < NCAND; ++t) {
        float m = -1e30f; int mpos = -1, midx = 0x7fffffff;
        for (int e = lane; e < 384; e += 64) {
            float v = sv[e]; int ix = si[e];
            if (v > m || (v == m && ix < midx)) { m = v; mpos = e; midx = ix; }
        }
#pragma unroll
        for (int off = 32; off; off >>= 1) {
            float ov = __shfl_xor(m, off);
            int   op = __shfl_xor(mpos, off);
            int   oi = __shfl_xor(midx, off);
            if (ov > m || (ov == m && oi < midx)) { m = ov; mpos = op; midx = oi; }
        }
        if (lane == 0) {
            cand[row * NCAND + t] = midx;
            topv[t] = m; topi[t] = midx;
            sv[mpos] = -1e30f;
        }
        __syncthreads();
    }
    if (lane == 0) {
        if (topv[KNN - 1] - topv[KNN] >= GAP_THRESH) {
#pragma unroll
            for (int t = 0; t < KNN; ++t) idx6[row * KNN + t] = topi[t];
        } else {
            int p = atomicAdd(cnt, 1);
            wl[p] = row;
        }
    }
}

// ---------------------------------------------------------------------------
// Exact (f64) rescore of ambiguous rows only (worklist-driven; early-exit
// past count). 256 threads, wave w handles candidates w, w+4, w+8.
__global__ void rescore_kernel(const float* __restrict__ x,
                               const double* __restrict__ invnorm,
                               const int* __restrict__ cand,
                               const int* __restrict__ wl,
                               const int* __restrict__ cnt,
                               int* __restrict__ idx6) {
    if (blockIdx.x >= *cnt) return;          // uniform per block
    int row = wl[blockIdx.x];
    int tid = threadIdx.x;                   // 256 threads
    int wave = tid >> 6, lane = tid & 63;
    __shared__ float4 xi4[DIM / 4];
    __shared__ double simv[NCAND];
    __shared__ int    cnd[NCAND];
    const float4* xr4 = (const float4*)(x + (size_t)row * DIM);
    xi4[tid] = xr4[tid]; xi4[tid + 256] = xr4[tid + 256];
    if (tid < NCAND) cnd[tid] = cand[row * NCAND + tid];
    __syncthreads();
    for (int t = wave; t < NCAND; t += 4) {
        int j = cnd[t];
        if (j == row) { if (lane == 0) simv[t] = 1e30; continue; }  // self: rank 1
        const float4* xj4 = (const float4*)(x + (size_t)j * DIM);
        double s = 0.0;
        for (int k = lane; k < DIM / 4; k += 64) {
            float4 a = xj4[k], bq = xi4[k];
            s += (double)a.x * bq.x + (double)a.y * bq.y +
                 (double)a.z * bq.z + (double)a.w * bq.w;
        }
#pragma unroll
        for (int off = 32; off; off >>= 1) s += __shfl_xor(s, off);
        if (lane == 0) simv[t] = s * invnorm[row] * invnorm[j];
    }
    __syncthreads();
    if (tid == 0) {
        double vals[NCAND]; int idxs[NCAND];
        for (int t = 0; t < NCAND; ++t) { vals[t] = simv[t]; idxs[t] = cnd[t]; }
        for (int t = 0; t < KNN; ++t) {
            int best = 0; double bvv = -1e300; int bji = 0x7fffffff;
            for (int e = 0; e < NCAND; ++e) {
                if (vals[e] > bvv || (vals[e] == bvv && idxs[e] < bji)) {
                    bvv = vals[e]; best = e; bji = idxs[e];
                }
            }
            idx6[row * KNN + t] = idxs[best];
            vals[best] = -1e300;
        }
    }
}

// ---------------------------------------------------------------------------
// GIN aggregation with reciprocal mask: h0 = 1.3*x_i + sum reciprocal x_j -> bf16
__global__ void aggregate_kernel(const float* __restrict__ x,
                                 const int* __restrict__ idx6,
                                 __hip_bfloat16* __restrict__ h0) {
    int row = blockIdx.x, tid = threadIdx.x;   // 256 threads
    __shared__ int nb[KNN];
    __shared__ int fl[KNN];
    if (tid < KNN) {
        int j = idx6[row * KNN + tid];
        nb[tid] = j;
        int f = 0;
        for (int t = 0; t < KNN; ++t) if (idx6[j * KNN + t] == row) f = 1;
        fl[tid] = f;
    }
    __syncthreads();
    int f0 = tid * 8;
    const float4* xr4 = (const float4*)(x + (size_t)row * DIM + f0);
    float4 a0 = xr4[0], a1 = xr4[1];
    float acc[8] = {1.3f * a0.x, 1.3f * a0.y, 1.3f * a0.z, 1.3f * a0.w,
                    1.3f * a1.x, 1.3f * a1.y, 1.3f * a1.z, 1.3f * a1.w};
    for (int t = 0; t < KNN; ++t) {
        if (fl[t]) {
            const float4* xj4 = (const float4*)(x + (size_t)nb[t] * DIM + f0);
            float4 b0 = xj4[0], b1 = xj4[1];
            acc[0] += b0.x; acc[1] += b0.y; acc[2] += b0.z; acc[3] += b0.w;
            acc[4] += b1.x; acc[5] += b1.y; acc[6] += b1.z; acc[7] += b1.w;
        }
    }
#pragma unroll
    for (int u = 0; u < 8; ++u)
        h0[(size_t)row * DIM + f0 + u] = __float2bfloat16(acc[u]);
}

// ---------------------------------------------------------------------------
__global__ void bn_finalize_kernel(float* __restrict__ stats,
                                   const float* __restrict__ gamma,
                                   const float* __restrict__ beta) {
    int c = blockIdx.x * 256 + threadIdx.x;         // 2048
    float mean = stats[c] * (1.0f / 8192.0f);
    float var  = stats[DIM + c] * (1.0f / 8192.0f) - mean * mean;
    float sc   = gamma[c] / sqrtf(var + 1e-5f);
    stats[2 * DIM + c] = sc;                        // scale
    stats[3 * DIM + c] = beta[c] - mean * sc;       // shift
}

// Fold BN into classifier: wcs[c,k] = wc[c,k]*scale[k] (bf16, zero-padded rows),
// lb[c] = sum_k shift[k]*wc[c,k].
__global__ void wc_fold_kernel(const float* __restrict__ wc,
                               const float* __restrict__ stats,
                               __hip_bfloat16* __restrict__ wcs,
                               float* __restrict__ lb) {
    int r = blockIdx.x, tid = threadIdx.x;          // 768 blocks x 256
    int k0 = tid * 8;
    float part = 0.f;
    if (r < NCLS) {
#pragma unroll
        for (int u = 0; u < 8; ++u) {
            int k = k0 + u;
            float w = wc[(size_t)r * DIM + k];
            wcs[(size_t)r * DIM + k] = __float2bfloat16(w * stats[2 * DIM + k]);
            part += w * stats[3 * DIM + k];
        }
    } else {
#pragma unroll
        for (int u = 0; u < 8; ++u)
            wcs[(size_t)r * DIM + k0 + u] = __float2bfloat16(0.f);
    }
    __shared__ float red[256];
    red[tid] = part; __syncthreads();
    for (int off = 128; off; off >>= 1) {
        if (tid < off) red[tid] += red[tid + off];
        __syncthreads();
    }
    if (tid == 0) lb[r] = red[0];
}

// ---------------------------------------------------------------------------
__global__ void f32_to_bf16_kernel(const float* __restrict__ src,
                                   __hip_bfloat16* __restrict__ dst, int n4) {
    int i = blockIdx.x * 256 + threadIdx.x;
    if (i < n4) {
        float4 v = ((const float4*)src)[i];
        __hip_bfloat16* o = dst + (size_t)i * 4;
        o[0] = __float2bfloat16(v.x); o[1] = __float2bfloat16(v.y);
        o[2] = __float2bfloat16(v.z); o[3] = __float2bfloat16(v.w);
    }
}

// ---------------------------------------------------------------------------
extern "C" void kernel_launch(void* const* d_in, const int* in_sizes, int n_in,
                              void* d_out, int out_size, void* d_ws, size_t ws_size,
                              hipStream_t stream) {
    const float* x     = (const float*)d_in[0];
    const float* w1    = (const float*)d_in[1];
    const float* b1    = (const float*)d_in[2];
    const float* w2    = (const float*)d_in[3];
    const float* b2    = (const float*)d_in[4];
    const float* gamma = (const float*)d_in[5];
    const float* beta  = (const float*)d_in[6];
    const float* wc    = (const float*)d_in[7];
    float* out = (float*)d_out;

    char* ws = (char*)d_ws;
    size_t off = 0;
    auto alloc = [&](size_t bytes) -> void* {
        void* p = ws + off;
        off += (bytes + 255) & ~(size_t)255;
        return p;
    };

    __hip_bfloat16* xnb  = (__hip_bfloat16*)alloc((size_t)N_ROWS * DIM * 2);    // 32 MB (reused: h0)
    __hip_bfloat16* S    = (__hip_bfloat16*)alloc((size_t)N_ROWS * N_ROWS * 2); // 128 MB (reused: z1, z2b)
    double*         invn = (double*)alloc((size_t)N_ROWS * 8);
    int*            cand = (int*)alloc((size_t)N_ROWS * NCAND * 4);
    int*            idx6 = (int*)alloc((size_t)N_ROWS * KNN * 4);
    __hip_bfloat16* w1b  = (__hip_bfloat16*)alloc((size_t)DIM * DIM * 2);
    __hip_bfloat16* w2b  = (__hip_bfloat16*)alloc((size_t)DIM * DIM * 2);
    __hip_bfloat16* wcs  = (__hip_bfloat16*)alloc((size_t)NPAD * DIM * 2);
    float*          lb   = (float*)alloc((size_t)NPAD * 4);
    float*          stats = (float*)alloc((size_t)4 * DIM * 4);
    int*            wl   = (int*)alloc((size_t)N_ROWS * 4);
    int*            cnt  = (int*)alloc((size_t)256);

    __hip_bfloat16* h0  = xnb;                          // xn dead after syrk
    __hip_bfloat16* z1  = S;                            // S dead after topk
    __hip_bfloat16* z2b = S + (size_t)N_ROWS * DIM;     // next 32 MB of S region

    hipMemsetAsync(stats, 0, 2 * DIM * sizeof(float), stream);
    hipMemsetAsync(cnt, 0, sizeof(int), stream);

    normalize_kernel<<<N_ROWS, 256, 0, stream>>>(x, xnb, invn);
    f32_to_bf16_kernel<<<(DIM * DIM / 4) / 256, 256, 0, stream>>>(w1, w1b, DIM * DIM / 4);
    f32_to_bf16_kernel<<<(DIM * DIM / 4) / 256, 256, 0, stream>>>(w2, w2b, DIM * DIM / 4);

    // S = xn xn^T, upper-triangle tiles only (+transposed writes)
    gemm_syrk<<<2080, 256, 0, stream>>>(xnb, S);

    topk_cand_kernel<<<N_ROWS, 64, 0, stream>>>(S, cand, idx6, wl, cnt);
    rescore_kernel<<<N_ROWS, 256, 0, stream>>>(x, invn, cand, wl, cnt, idx6);
    aggregate_kernel<<<N_ROWS, 256, 0, stream>>>(x, idx6, h0);

    // z1 = relu(h0 @ w1^T + b1)   [bf16]
    gemm_nt<1, 128><<<dim3(DIM / 128, N_ROWS / 128), 256, 0, stream>>>(
        h0, w1b, (void*)z1, b1, nullptr, DIM, DIM, 0);
    // z2b = h@w2^T + b2 [bf16] with fused BN column stats
    gemm_nt<4, 128><<<dim3(DIM / 128, N_ROWS / 128), 256, 0, stream>>>(
        z1, w2b, (void*)z2b, b2, stats, DIM, DIM, 0);

    bn_finalize_kernel<<<DIM / 256, 256, 0, stream>>>(stats, gamma, beta);
    wc_fold_kernel<<<NPAD, 256, 0, stream>>>(wc, stats, wcs, lb);

    // logits = (z2*scale+shift) @ wc^T = z2b @ wcs^T + lb   [fp32, col<751]
    gemm_nt<5, 64><<<dim3(NPAD / 128, N_ROWS / 64), 256, 0, stream>>>(
        z2b, wcs, (void*)out, lb, nullptr, DIM, NCLS, NCLS);
}